// Round 7
// baseline (312.754 us; speedup 1.0000x reference)
//
#include <hip/hip_runtime.h>
#include <math.h>

#define Vn 5
#define Cn 32
#define Hn 384
#define Wn 384
#define Dn 4
#define Gn 8
#define HWn (Hn*Wn)   // 147456

typedef _Float16 h2 __attribute__((ext_vector_type(2)));

__device__ __forceinline__ float fdot2h(h2 a, h2 b, float c){
#if __has_builtin(__builtin_amdgcn_fdot2)
    return __builtin_amdgcn_fdot2(a, b, c, false);
#else
    return (float)a.x*(float)b.x + (float)a.y*(float)b.y + c;
#endif
}
__device__ __forceinline__ h2 pkh(float a, float b){   // fast pack (RTZ)
#if __has_builtin(__builtin_amdgcn_cvt_pkrtz)
    return __builtin_bit_cast(h2, __builtin_amdgcn_cvt_pkrtz(a, b));
#else
    h2 r; r.x = (_Float16)a; r.y = (_Float16)b; return r;
#endif
}
__device__ __forceinline__ unsigned int packh2(float a, float b){  // accurate pack (RNE)
    h2 h;
    h.x = (_Float16)a;
    h.y = (_Float16)b;
    return __builtin_bit_cast(unsigned int, h);
}
__device__ __forceinline__ h2 bch2(unsigned int u){ return __builtin_bit_cast(h2, u); }

// ---------- small 3x3 helpers (device) ----------
__device__ __forceinline__ void inv3(const float* m, float* o){
    float a=m[0],b=m[1],c=m[2],d=m[3],e=m[4],f=m[5],g=m[6],h=m[7],i=m[8];
    float A =  e*i - f*h;
    float B = -(d*i - f*g);
    float C =  d*h - e*g;
    float det = a*A + b*B + c*C;
    float r = 1.f/det;
    o[0] = A*r;            o[1] = -(b*i - c*h)*r;  o[2] =  (b*f - c*e)*r;
    o[3] = B*r;            o[4] =  (a*i - c*g)*r;  o[5] = -(a*f - c*d)*r;
    o[6] = C*r;            o[7] = -(a*h - b*g)*r;  o[8] =  (a*e - b*d)*r;
}
__device__ __forceinline__ void mm3(const float* a, const float* b, float* o){
    #pragma unroll
    for (int r=0;r<3;r++)
        #pragma unroll
        for (int c=0;c<3;c++)
            o[r*3+c] = a[r*3+0]*b[0*3+c] + a[r*3+1]*b[1*3+c] + a[r*3+2]*b[2*3+c];
}
__device__ __forceinline__ void mv3(const float* a, const float* v, float* o){
    #pragma unroll
    for (int r=0;r<3;r++)
        o[r] = a[r*3+0]*v[0] + a[r*3+1]*v[1] + a[r*3+2]*v[2];
}

// ---------- transpose+convert source views (C,H,W) fp32 -> (H*W, C) f16 ----------
__global__ __launch_bounds__(256)
void transpose_kernel(const float* __restrict__ feat, unsigned short* __restrict__ featT){
    __shared__ float tile[32][257];
    const int s  = blockIdx.y;            // 0..3 -> view s+1
    const int p0 = blockIdx.x * 256;      // pixel tile base
    const int t  = threadIdx.x;
    const float* src = feat + (size_t)(s+1)*Cn*HWn + p0;
    #pragma unroll
    for (int k=0;k<8;k++){
        const int i   = k*256 + t;
        const int px4 = (i & 63) * 4;
        const int ch  = i >> 6;
        const float4 v = *(const float4*)(src + (size_t)ch*HWn + px4);
        tile[ch][px4+0]=v.x; tile[ch][px4+1]=v.y; tile[ch][px4+2]=v.z; tile[ch][px4+3]=v.w;
    }
    __syncthreads();
    uint4* dst = (uint4*)(featT + ((size_t)s*HWn + p0 + t)*Cn);
    #pragma unroll
    for (int q=0;q<4;q++){
        uint4 o;
        o.x = packh2(tile[8*q+0][t], tile[8*q+1][t]);
        o.y = packh2(tile[8*q+2][t], tile[8*q+3][t]);
        o.z = packh2(tile[8*q+4][t], tile[8*q+5][t]);
        o.w = packh2(tile[8*q+6][t], tile[8*q+7][t]);
        dst[q] = o;
    }
}

// one tap: lane loads ITS 16B quarter of the 64B record (4 quad-lanes coalesce
// into one cache line); 2 groups per quarter
#define TAPQ(w_, xi_, yi_, Sv, d_)                                                   \
    if ((w_) != 0.f){                                                                \
        const uint4 qd = *(const uint4*)(vb + (size_t)((yi_)*Wn + (xi_))*Cn + q8);   \
        const float dtA = fdot2h(bch2(qd.x), r2a, fdot2h(bch2(qd.y), r2b, 0.f));     \
        const float dtB = fdot2h(bch2(qd.z), r2c, fdot2h(bch2(qd.w), r2d, 0.f));     \
        Sv[2*(d_)+0] = fmaf((w_), dtA, Sv[2*(d_)+0]);                                \
        Sv[2*(d_)+1] = fmaf((w_), dtB, Sv[2*(d_)+1]);                                \
    }

// all 4 depths of one view; v_ is a compile-time literal
#define VIEW_BODY(v_, Sv)                                                            \
    {                                                                                \
        const float* M = &sM[(v_)*12];                                               \
        const float bx = M[0]*xg + M[1]*yg + M[2];                                   \
        const float by = M[3]*xg + M[4]*yg + M[5];                                   \
        const float bz = M[6]*xg + M[7]*yg + M[8];                                   \
        const float cx = M[9], cy = M[10], cz = M[11];                               \
        const unsigned short* vb = featT + (size_t)(v_)*HWn*Cn;                      \
        _Pragma("unroll")                                                            \
        for (int d=0; d<Dn; d++){                                                    \
            const float dd = dep[d];                                                 \
            const float ux = fmaf(bx, dd, cx);                                       \
            const float uy = fmaf(by, dd, cy);                                       \
            const float uz = fmaf(bz, dd, cz) + 1e-9f;                               \
            const float rz = 1.f/uz;                                                 \
            const float px = ux*rz, py = uy*rz;                                      \
            const float x0 = floorf(px), y0 = floorf(py);                            \
            const float wx1 = px - x0, wy1 = py - y0;                                \
            const float wx0 = 1.f - wx1, wy0 = 1.f - wy1;                            \
            const bool vx0 = (x0 >= 0.f)  && (x0 <= (float)(Wn-1));                  \
            const bool vx1 = (x0 >= -1.f) && (x0 <= (float)(Wn-2));                  \
            const bool vy0 = (y0 >= 0.f)  && (y0 <= (float)(Hn-1));                  \
            const bool vy1 = (y0 >= -1.f) && (y0 <= (float)(Hn-2));                  \
            const float w00 = (vx0&&vy0) ? 0.25f*wx0*wy0 : 0.f;                      \
            const float w10 = (vx1&&vy0) ? 0.25f*wx1*wy0 : 0.f;                      \
            const float w01 = (vx0&&vy1) ? 0.25f*wx0*wy1 : 0.f;                      \
            const float w11 = (vx1&&vy1) ? 0.25f*wx1*wy1 : 0.f;                      \
            const int xi0 = (int)fminf(fmaxf(x0,     0.f), (float)(Wn-1));           \
            const int xi1 = (int)fminf(fmaxf(x0+1.f, 0.f), (float)(Wn-1));           \
            const int yi0 = (int)fminf(fmaxf(y0,     0.f), (float)(Hn-1));           \
            const int yi1 = (int)fminf(fmaxf(y0+1.f, 0.f), (float)(Hn-1));           \
            TAPQ(w00, xi0, yi0, Sv, d)                                               \
            TAPQ(w10, xi1, yi0, Sv, d)                                               \
            TAPQ(w01, xi0, yi1, Sv, d)                                               \
            TAPQ(w11, xi1, yi1, Sv, d)                                               \
        }                                                                            \
    }

// ---------- fused main kernel: one thread per (pixel, record-quarter) ----------
// Block = 256 threads = 64 pixels x 4 quarter-lanes. Each lane loads 16B/tap
// (its 8 channels) for ALL 4 views; a 4x4 shfl_xor lane-transpose then gives
// lane q the full 8-group sim of view q for the MLP stage.
__global__ __launch_bounds__(256, 2)
void gbinet_kernel(const float* __restrict__ feat,
                   const float* __restrict__ depths,
                   const float* __restrict__ Kin,
                   const float* __restrict__ Ein,
                   const float* __restrict__ w0, const float* __restrict__ b0,
                   const float* __restrict__ w1, const float* __restrict__ b1,
                   const float* __restrict__ w2, const float* __restrict__ b2,
                   const unsigned short* __restrict__ featT,
                   float* __restrict__ out)
{
    __shared__ unsigned int sW0h[64], sW1h[64], sW2h[4];
    __shared__ float sB0[16], sB1[8], sB2s[1];
    __shared__ float sM[48];            // per source view: A[9] + c[3]
    __shared__ float sRef[64*33];       // 64 pixels x 32 ref channels (pad 33)
    __shared__ float sDep[4*65];        // 4 depth planes x 64 pixels (pad 65)
    __shared__ float sOut[64*33];       // 64 pixels x 32 outputs (pad 33)
    const int t = threadIdx.x;
    if (t < 64)       sW0h[t]    = packh2(w0[2*t], w0[2*t+1]);
    else if (t < 128){ const int i = t-64; sW1h[i] = packh2(w1[2*i], w1[2*i+1]); }
    if (t < 4)  sW2h[t] = packh2(w2[2*t], w2[2*t+1]);
    if (t < 16) sB0[t] = b0[t];
    if (t < 8)  sB1[t] = b1[t];

    // cooperative coalesced stage of ref (view0 fp32) and depths for 64 pixels
    const int blockBase = blockIdx.x * 64;
    {
        const float* srcR = feat + blockBase;
        #pragma unroll
        for (int k=0;k<8;k++){
            const int i  = k*256 + t;
            const int c  = i >> 6;
            const int px = i & 63;
            sRef[px*33 + c] = srcR[(size_t)c*HWn + px];
        }
        const int dp = t >> 6;          // 0..3
        const int px = t & 63;
        sDep[dp*65 + px] = depths[(size_t)dp*HWn + blockBase + px];
    }

    if (t == 0){
        sB2s[0] = b2[0];
        // fold projection chain: uvd = A_s * (x,y,1) * depth + c_s
        float K0inv[9]; inv3(Kin, K0inv);
        float R0[9], t0[3];
        #pragma unroll
        for (int r=0;r<3;r++){
            #pragma unroll
            for (int c=0;c<3;c++) R0[r*3+c] = Ein[r*4+c];
            t0[r] = Ein[r*4+3];
        }
        float R0inv[9]; inv3(R0, R0inv);
        float M0[9]; mm3(R0inv, K0inv, M0);
        float Rt0[3]; mv3(R0inv, t0, Rt0);
        for (int s=1;s<Vn;s++){
            const float* Ks = Kin + s*9;
            const float* Es = Ein + s*12;
            float Rs[9], ts[3];
            #pragma unroll
            for (int r=0;r<3;r++){
                #pragma unroll
                for (int c=0;c<3;c++) Rs[r*3+c] = Es[r*4+c];
                ts[r] = Es[r*4+3];
            }
            float T1[9]; mm3(Rs, M0, T1);
            float A[9];  mm3(Ks, T1, A);
            float Rr[3]; mv3(Rs, Rt0, Rr);
            float tv[3] = { ts[0]-Rr[0], ts[1]-Rr[1], ts[2]-Rr[2] };
            float cv[3]; mv3(Ks, tv, cv);
            float* dm = &sM[(s-1)*12];
            #pragma unroll
            for (int i=0;i<9;i++) dm[i] = A[i];
            #pragma unroll
            for (int i=0;i<3;i++) dm[9+i] = cv[i];
        }
    }
    __syncthreads();

    const int pixQ = t >> 2;            // 0..63
    const int q    = t & 3;             // record quarter (channels 8q..8q+7)
    const int q8   = q * 8;
    const int pix  = blockBase + pixQ;
    const float xg = (float)(pix % Wn) + 0.5f;
    const float yg = (float)(pix / Wn) + 0.5f;

    // my 8 ref channels as 4 packed half2
    const h2 r2a = pkh(sRef[pixQ*33 + q8+0], sRef[pixQ*33 + q8+1]);
    const h2 r2b = pkh(sRef[pixQ*33 + q8+2], sRef[pixQ*33 + q8+3]);
    const h2 r2c = pkh(sRef[pixQ*33 + q8+4], sRef[pixQ*33 + q8+5]);
    const h2 r2d = pkh(sRef[pixQ*33 + q8+6], sRef[pixQ*33 + q8+7]);
    float dep[Dn];
    #pragma unroll
    for (int d=0;d<Dn;d++) dep[d] = sDep[d*65 + pixQ];

    // S{v}[2d+j] = sim partial for group (2q+j), view v, depth d
    float S0[8], S1[8], S2[8], S3[8];
    #pragma unroll
    for (int k=0;k<8;k++){ S0[k]=0.f; S1[k]=0.f; S2[k]=0.f; S3[k]=0.f; }

    VIEW_BODY(0, S0)
    VIEW_BODY(1, S1)
    VIEW_BODY(2, S2)
    VIEW_BODY(3, S3)

    // 4x4 lane transpose over the quad: after this, S{v}[2d+j] on lane q holds
    // group (2v+j), view q, depth d.
    {
        const bool c0 = (q & 1);
        #pragma unroll
        for (int k=0;k<8;k++){
            const float p0 = __shfl_xor(S1[k], 1);
            const float p1 = __shfl_xor(S0[k], 1);
            const float p2 = __shfl_xor(S3[k], 1);
            const float p3 = __shfl_xor(S2[k], 1);
            const float n0 = c0 ? p0 : S0[k];
            const float n1 = c0 ? S1[k] : p1;
            const float n2 = c0 ? p2 : S2[k];
            const float n3 = c0 ? S3[k] : p3;
            S0[k]=n0; S1[k]=n1; S2[k]=n2; S3[k]=n3;
        }
        const bool c1 = (q & 2);
        #pragma unroll
        for (int k=0;k<8;k++){
            const float p0 = __shfl_xor(S2[k], 2);
            const float p1 = __shfl_xor(S3[k], 2);
            const float p2 = __shfl_xor(S0[k], 2);
            const float p3 = __shfl_xor(S1[k], 2);
            const float n0 = c1 ? p0 : S0[k];
            const float n1 = c1 ? p1 : S1[k];
            const float n2 = c1 ? S2[k] : p2;
            const float n3 = c1 ? S3[k] : p3;
            S0[k]=n0; S1[k]=n1; S2[k]=n2; S3[k]=n3;
        }
    }

    // pixelwise net (view q) over 4 depths with packed f16 dots;
    // max(sigmoid) == sigmoid(max logit)
    float maxlog = -3.0e38f;
    #pragma unroll
    for (int d=0; d<Dn; d++){
        const h2 s0 = pkh(S0[2*d], S0[2*d+1]);
        const h2 s1 = pkh(S1[2*d], S1[2*d+1]);
        const h2 s2 = pkh(S2[2*d], S2[2*d+1]);
        const h2 s3 = pkh(S3[2*d], S3[2*d+1]);
        float h[16];
        #pragma unroll
        for (int o=0;o<16;o++){
            float a = sB0[o];
            a = fdot2h(bch2(sW0h[o*4+0]), s0, a);
            a = fdot2h(bch2(sW0h[o*4+1]), s1, a);
            a = fdot2h(bch2(sW0h[o*4+2]), s2, a);
            a = fdot2h(bch2(sW0h[o*4+3]), s3, a);
            h[o] = fmaxf(a, 0.f);
        }
        h2 hp[8];
        #pragma unroll
        for (int i=0;i<8;i++) hp[i] = pkh(h[2*i], h[2*i+1]);
        float g8[8];
        #pragma unroll
        for (int o=0;o<8;o++){
            float a = sB1[o];
            #pragma unroll
            for (int i=0;i<8;i++) a = fdot2h(bch2(sW1h[o*8+i]), hp[i], a);
            g8[o] = fmaxf(a, 0.f);
        }
        float lg = sB2s[0];
        #pragma unroll
        for (int i=0;i<4;i++) lg = fdot2h(bch2(sW2h[i]), pkh(g8[2*i], g8[2*i+1]), lg);
        maxlog = fmaxf(maxlog, lg);
    }
    const float vw = 1.f/(1.f + __expf(-maxlog));

    // scale by vw, butterfly-reduce across the quad (views), lane q==0 writes
    float wsum = vw;
    wsum += __shfl_xor(wsum, 1);
    wsum += __shfl_xor(wsum, 2);
    const float invw = 1.f/wsum;
    #pragma unroll
    for (int k=0;k<8;k++){
        float v0 = S0[k]*vw, v1 = S1[k]*vw, v2 = S2[k]*vw, v3 = S3[k]*vw;
        v0 += __shfl_xor(v0, 1); v0 += __shfl_xor(v0, 2);
        v1 += __shfl_xor(v1, 1); v1 += __shfl_xor(v1, 2);
        v2 += __shfl_xor(v2, 1); v2 += __shfl_xor(v2, 2);
        v3 += __shfl_xor(v3, 1); v3 += __shfl_xor(v3, 2);
        if (q == 0){
            const int d = k >> 1, j = k & 1;
            sOut[pixQ*33 + (0+j)*Dn + d] = v0*invw;
            sOut[pixQ*33 + (2+j)*Dn + d] = v1*invw;
            sOut[pixQ*33 + (4+j)*Dn + d] = v2*invw;
            sOut[pixQ*33 + (6+j)*Dn + d] = v3*invw;
        }
    }
    __syncthreads();

    // coalesced write-out: 32 planes x 64 pixels
    float* oBase = out + blockBase;
    #pragma unroll
    for (int k=0;k<8;k++){
        const int e     = k*256 + t;
        const int plane = e >> 6;
        const int pixel = e & 63;
        oBase[(size_t)plane*HWn + pixel] = sOut[pixel*33 + plane];
    }
}

extern "C" void kernel_launch(void* const* d_in, const int* in_sizes, int n_in,
                              void* d_out, int out_size, void* d_ws, size_t ws_size,
                              hipStream_t stream)
{
    (void)in_sizes; (void)n_in; (void)out_size; (void)ws_size;
    const float* feat   = (const float*)d_in[0];
    const float* depths = (const float*)d_in[1];
    const float* K      = (const float*)d_in[2];
    const float* E      = (const float*)d_in[3];
    const float* w0     = (const float*)d_in[4];
    const float* b0     = (const float*)d_in[5];
    const float* w1     = (const float*)d_in[6];
    const float* b1     = (const float*)d_in[7];
    const float* w2     = (const float*)d_in[8];
    const float* b2     = (const float*)d_in[9];
    float* out = (float*)d_out;
    unsigned short* featT = (unsigned short*)d_ws;   // (V-1, HW, C) f16 = 37.7 MB

    dim3 g(HWn/256, Vn-1);
    transpose_kernel<<<g, 256, 0, stream>>>(feat, featT);
    gbinet_kernel<<<HWn/64, 256, 0, stream>>>(feat, depths, K, E,
                                              w0,b0,w1,b1,w2,b2, featT, out);
}